// Round 10
// baseline (475.900 us; speedup 1.0000x reference)
//
#include <hip/hip_runtime.h>

typedef unsigned short u16;
typedef __attribute__((ext_vector_type(4))) float f32x4;
typedef __attribute__((ext_vector_type(8))) __bf16 bf16x8;
typedef __attribute__((ext_vector_type(8))) u16 u16x8;

#define ALPHA_F 0.1f

// Cl(3,0): e_a * e_c = (-1)^p e_{a^c}  [validated R1-R9]
__device__ __host__ constexpr bool SGN(int a, int c) {
  return ((((c & 1) & (((a >> 1) ^ (a >> 2)) & 1)) ^
           (((c >> 1) & 1) & ((a >> 2) & 1))) != 0);
}
__device__ __host__ constexpr float REVF(int c) {
  const int r = (c & 1) + ((c >> 1) & 1) + ((c >> 2) & 1);
  return (r >= 2) ? -1.f : 1.f;
}
__device__ __forceinline__ u16 bf_rnd(float f) {
  unsigned u = __float_as_uint(f);
  return (u16)((u + 0x7FFFu + ((u >> 16) & 1u)) >> 16);
}
__device__ __forceinline__ float bf_val(u16 h) {
  return __uint_as_float(((unsigned)h) << 16);
}
__device__ __forceinline__ f32x4 mf(bf16x8 a, bf16x8 b, f32x4 c) {
  return __builtin_amdgcn_mfma_f32_16x16x32_bf16(a, b, c, 0, 0, 0);
}
__device__ __forceinline__ bf16x8 negf(bf16x8 v) {
  u16x8 u = __builtin_bit_cast(u16x8, v);
  const u16x8 m = {0x8000, 0x8000, 0x8000, 0x8000, 0x8000, 0x8000, 0x8000, 0x8000};
  u = u ^ m;
  return __builtin_bit_cast(bf16x8, u);
}

// ===========================================================================
// D1: pack raw inputs (validated R8/R9). UNCHANGED.
// ===========================================================================
__global__ __launch_bounds__(256) void pack_in(
    const float* __restrict__ x, const float* __restrict__ w1,
    const float* __restrict__ w2, u16* P1h, u16* P1l, u16* Q1, u16* Qc1,
    u16* P2h, u16* P2l, u16* Q2, u16* Axh, u16* Axl, u16* Vpk2, u16* Z0h,
    u16* Z0l, float* out0) {
  const int t = blockIdx.x * 256 + threadIdx.x;
  if (t < 131072) {  // Q1 + Qc1 (cc-fast): r = m, cc = n'
    const int r = t >> 9, cc = t & 511;
    const float* s = w1 + ((size_t)r * 512 + cc) * 8;
    float v[8];
#pragma unroll
    for (int c = 0; c < 8; ++c) v[c] = s[c];
    const size_t qo = (size_t)((cc >> 4) * 2 + (r >> 7)) * 32768 +
                      ((r >> 5) & 3) * 512 + ((r >> 3) & 3) * 128 +
                      (cc & 15) * 8 + (r & 7);
#pragma unroll
    for (int c = 0; c < 8; ++c) {
      const float q1 = REVF(c) * v[c];
      u16 h = bf_rnd(q1);
      Q1[qo + c * 4096] = h;
      Q1[qo + c * 4096 + 2048] = bf_rnd(q1 - bf_val(h));
      const float qc = ALPHA_F * q1;
      h = bf_rnd(qc);
      Qc1[qo + c * 4096] = h;
      Qc1[qo + c * 4096 + 2048] = bf_rnd(qc - bf_val(h));
    }
  } else if (t < 262144) {  // Q2 + Wcat-bottom (c2-fast): r = m, c2 = j
    const int u = t - 131072;
    const int r = u >> 8, c2 = u & 255;
    const float* s = w2 + ((size_t)r * 256 + c2) * 8;
    float v[8];
#pragma unroll
    for (int c = 0; c < 8; ++c) v[c] = s[c];
    const size_t tail = ((r >> 5) & 3) * 512 + ((r >> 3) & 3) * 128 +
                        (c2 & 15) * 8 + (r & 7);
    const size_t qo = (size_t)((c2 >> 4) * 4 + (r >> 7)) * 32768 + tail;
    const size_t wo = (size_t)((c2 >> 4) * 6 + 2 + (r >> 7)) * 32768 + tail;
#pragma unroll
    for (int c = 0; c < 8; ++c) {
      const float q2 = REVF(c) * v[c];
      u16 h = bf_rnd(q2);
      Q2[qo + c * 4096] = h;
      Q2[qo + c * 4096 + 2048] = bf_rnd(q2 - bf_val(h));
      const float qw = ALPHA_F * q2;
      h = bf_rnd(qw);
      Vpk2[wo + c * 4096] = h;
      Vpk2[wo + c * 4096 + 2048] = bf_rnd(qw - bf_val(h));
    }
  } else if (t < 393216) {  // P1 planes, r-fast (coalesced writes)
    const int u = t - 262144;
    const int r = u & 255, cc = u >> 8;
    const float* s = w1 + ((size_t)r * 512 + cc) * 8;
#pragma unroll
    for (int a = 0; a < 8; ++a) {
      const float v = s[a];
      const u16 h = bf_rnd(v);
      P1h[((size_t)a * 512 + cc) * 256 + r] = h;
      P1l[((size_t)a * 512 + cc) * 256 + r] = bf_rnd(v - bf_val(h));
    }
  } else if (t < 524288) {  // P2 planes, r-fast
    const int u = t - 393216;
    const int r = u & 511, c2 = u >> 9;
    const float* s = w2 + ((size_t)r * 256 + c2) * 8;
#pragma unroll
    for (int a = 0; a < 8; ++a) {
      const float v = s[a];
      const u16 h = bf_rnd(v);
      P2h[((size_t)a * 256 + c2) * 512 + r] = h;
      P2l[((size_t)a * 256 + c2) * 512 + r] = bf_rnd(v - bf_val(h));
    }
  } else if (t < 540672) {  // x planes [a][b][n]
    const int u = t - 524288;
    const int b = u >> 8, n = u & 255;
    const float* s = x + ((size_t)b * 256 + n) * 8;
#pragma unroll
    for (int a = 0; a < 8; ++a) {
      const u16 h = bf_rnd(s[a]);
      Axh[((size_t)a * 64 + b) * 256 + n] = h;
      Axl[((size_t)a * 64 + b) * 256 + n] = bf_rnd(s[a] - bf_val(h));
    }
  } else if (t < 573440) {  // out0 = x
    const int u = t - 540672;
    ((float4*)out0)[u] = ((const float4*)x)[u];
  } else if (t < 606208) {  // Z0 S2-region zero
    const int u = t - 573440;
    const int hl = u >> 14, i = u & 16383;
    const int a = i >> 11, j = i & 2047;
    const u16x8 z = {0, 0, 0, 0, 0, 0, 0, 0};
    u16* Z = hl ? Z0l : Z0h;
    *(u16x8*)&Z[(size_t)a * 49152 + (size_t)j * 8] = z;
  }
}

// ===========================================================================
// D2: composeK (validated R8/R9). UNCHANGED.
// ===========================================================================
__global__ __launch_bounds__(512, 2) void composeK(
    const u16* __restrict__ P1h, const u16* __restrict__ P1l,
    const u16* __restrict__ Q1, const u16* __restrict__ P2h,
    const u16* __restrict__ P2l, const u16* __restrict__ Q2,
    const u16* __restrict__ Axh, const u16* __restrict__ Axl,
    const u16* __restrict__ Qc1, u16* Vpk1, u16* Vpk2, u16* Z0h, u16* Z0l,
    float* c1Z) {
  __shared__ float pan[8][2048];

  const int bid = blockIdx.x, tid = threadIdx.x;
  const int w = tid >> 6, l = tid & 63;
  const int lg = l >> 4, lm = l & 15;

  int seg, rb, p;
  if (bid < 256) { seg = 1; rb = bid >> 4; p = bid & 15; }
  else if (bid < 1280) { seg = 0; rb = (bid - 256) >> 5; p = (bid - 256) & 31; }
  else { seg = 2; rb = (bid - 1280) >> 5; p = (bid - 1280) & 31; }

  const u16* Ah_ = seg == 0 ? P1h : (seg == 1 ? P2h : Axh);
  const u16* Al_ = seg == 0 ? P1l : (seg == 1 ? P2l : Axl);
  const u16* Vb = seg == 0 ? Q1 : (seg == 1 ? Q2 : Qc1);
  const int AROW = seg == 0 ? 512 : (seg == 1 ? 256 : 64);
  const int KT = seg == 1 ? 512 : 256;
  const int NW = seg == 1 ? 2 : 1;
  const int slmul = seg == 1 ? 4 : 2;
  const int row = rb * 16 + lm;

  f32x4 acc[8];
#pragma unroll
  for (int k = 0; k < 8; ++k) acc[k] = f32x4{0.f, 0.f, 0.f, 0.f};

  for (int wi = 0; wi < NW; ++wi) {
    const int n0 = w * (NW * 32) + wi * 32;
    const int sl = n0 >> 7, hst = (n0 >> 5) & 3;
    const u16* Vimg =
        Vb + ((size_t)(p * slmul + sl) << 15) + hst * 512 + lg * 128 + lm * 8;
    bf16x8 ah[8], al[8];
#pragma unroll
    for (int a = 0; a < 8; ++a) {
      const size_t o = ((size_t)(a * AROW + row)) * KT + n0 + lg * 8;
      ah[a] = *(const bf16x8*)(Ah_ + o);
      al[a] = *(const bf16x8*)(Al_ + o);
    }
#pragma unroll
    for (int c = 0; c < 8; ++c) {
      const bf16x8 vhp = *(const bf16x8*)(Vimg + (size_t)c * 4096);
      const bf16x8 vlp = *(const bf16x8*)(Vimg + (size_t)c * 4096 + 2048);
      const bf16x8 vhn = negf(vhp), vln = negf(vlp);
#pragma unroll
      for (int a = 0; a < 8; ++a) {
        const int k = a ^ c;
        const bf16x8 vh = SGN(a, c) ? vhn : vhp;
        const bf16x8 vl = SGN(a, c) ? vln : vlp;
        acc[k] = mf(ah[a], vh, acc[k]);
        acc[k] = mf(al[a], vh, acc[k]);
        acc[k] = mf(ah[a], vl, acc[k]);
      }
    }
  }

#pragma unroll
  for (int k = 0; k < 8; ++k)
#pragma unroll
    for (int q = 0; q < 4; ++q)
      pan[w][k * 256 + (lg * 4 + q) * 16 + lm] = acc[k][q];
  __syncthreads();

  if (tid < 256) {
    const int k = tid >> 5, rw = (tid >> 1) & 15, ch = tid & 1;
    const int boff = k * 256 + rw * 16 + ch * 8;
    f32x4 s0 = {0.f, 0.f, 0.f, 0.f}, s1 = {0.f, 0.f, 0.f, 0.f};
    for (int ss = 0; ss < 8; ++ss) {
      s0 += *(const f32x4*)&pan[ss][boff];
      s1 += *(const f32x4*)&pan[ss][boff + 4];
    }
    float v[8];
#pragma unroll
    for (int e = 0; e < 4; ++e) { v[e] = s0[e]; v[4 + e] = s1[e]; }
    const int n = rb * 16 + rw;

    if (seg <= 1) {
      u16* base = seg == 0 ? Vpk1 : Vpk2;
      const int blk = (seg == 0 ? p * 4 : p * 6) + (n >> 7);
      u16* d = base + ((size_t)blk << 15) + (size_t)k * 4096 +
               ((n >> 5) & 3) * 512 + ((n >> 3) & 3) * 128 + (n & 7);
#pragma unroll
      for (int e = 0; e < 8; ++e) {
        const int m = p * 16 + ch * 8 + e;
        const float val = ((k == 0) && (n == m) ? 1.0f : 0.0f) - ALPHA_F * v[e];
        const u16 hh = bf_rnd(val);
        d[(size_t)(ch * 8 + e) * 8] = hh;
        d[2048 + (size_t)(ch * 8 + e) * 8] = bf_rnd(val - bf_val(hh));
      }
    } else {
      const int b = n;
      float* cp_ = c1Z + (((size_t)k * 64 + p * 2 + ch) * 64 + b) * 8;
      u16x8 h8, l8;
#pragma unroll
      for (int e = 0; e < 8; ++e) {
        cp_[e] = v[e];
        const u16 hh = bf_rnd(v[e]);
        h8[e] = hh;
        l8[e] = bf_rnd(v[e] - bf_val(hh));
      }
      const size_t zo = (((size_t)k * 96 + 32 + p * 2 + ch) * 64 + b) * 8;
      *(u16x8*)&Z0h[zo] = h8;
      *(u16x8*)&Z0l[zo] = l8;
    }
  }
}

// ===========================================================================
// Main-loop pair kernel. R9 template + XCD-affine block remap:
//   p = rb & (npan-1), bh = rb >> log2(npan)
// => the 4 row-blocks sharing V-panel p land on the SAME XCD (bid stride 32/16
// is a multiple of 8), so V stays L2-resident across the entire chain.
// Pure index permutation — arithmetic identical to R7/R8/R9.
// ===========================================================================
struct IArgs {
  const u16 *Zch, *Zcl;
  u16 *Znh, *Znl;
  const u16 *Vpk1, *Vpk2;
  const float* c1Z;
  float *out1, *out2;
  int n_g1;
};

template <bool G1>
__device__ __forceinline__ void iter_body(const IArgs& A, int t18, int fin,
                                          float (*pan)[2048]) {
  const int bid = blockIdx.x, tid = threadIdx.x;
  const int w = tid >> 6, l = tid & 63;
  const int lg = l >> 4, lm = l & 15;
  const int rb = G1 ? bid : bid - A.n_g1;
  constexpr int NPAN = G1 ? 32 : 16;
  const int p = rb & (NPAN - 1);        // XCD-affine: same-p blocks same XCD
  const int bh = rb / NPAN;
  const int b0 = bh * 16;
  constexpr int KW = G1 ? 64 : 96;
  constexpr int NW = G1 ? 2 : 3;
  constexpr int acb0 = G1 ? 32 : 0;
  constexpr int slmul = G1 ? 4 : 6;
  const u16* Vb = G1 ? A.Vpk1 : A.Vpk2;

  f32x4 acc[8];
#pragma unroll
  for (int k = 0; k < 8; ++k) acc[k] = f32x4{0.f, 0.f, 0.f, 0.f};

#pragma unroll
  for (int wi = 0; wi < NW; ++wi) {
    const int n0 = w * KW + wi * 32;
    const int sl = n0 >> 7, hst = (n0 >> 5) & 3;
    const u16* Vimg = Vb + ((size_t)(p * slmul + sl) << 15) + hst * 512 +
                      lg * 128 + lm * 8;
    const size_t ao = ((size_t)(acb0 + (n0 >> 3) + lg) * 64 + b0 + lm) * 8;
    bf16x8 ah[8], al[8];
#pragma unroll
    for (int a = 0; a < 8; ++a) {
      ah[a] = *(const bf16x8*)(A.Zch + (size_t)a * 49152 + ao);
      al[a] = *(const bf16x8*)(A.Zcl + (size_t)a * 49152 + ao);
    }
#pragma unroll
    for (int c = 0; c < 8; ++c) {
      const bf16x8 vhp = *(const bf16x8*)(Vimg + (size_t)c * 4096);
      const bf16x8 vlp = *(const bf16x8*)(Vimg + (size_t)c * 4096 + 2048);
      const bf16x8 vhn = negf(vhp), vln = negf(vlp);
#pragma unroll
      for (int a = 0; a < 8; ++a) {
        const int k = a ^ c;
        const bf16x8 vh = SGN(a, c) ? vhn : vhp;
        const bf16x8 vl = SGN(a, c) ? vln : vlp;
        acc[k] = mf(ah[a], vh, acc[k]);
        acc[k] = mf(al[a], vh, acc[k]);
        acc[k] = mf(ah[a], vl, acc[k]);
      }
    }
  }

#pragma unroll
  for (int k = 0; k < 8; ++k)
#pragma unroll
    for (int q = 0; q < 4; ++q)
      pan[w][k * 256 + (lg * 4 + q) * 16 + lm] = acc[k][q];
  __syncthreads();

  if (tid < 256) {
    const int k = tid >> 5, row = (tid >> 1) & 15, ch = tid & 1;
    const int boff = k * 256 + row * 16 + ch * 8;
    f32x4 s0 = {0.f, 0.f, 0.f, 0.f}, s1 = {0.f, 0.f, 0.f, 0.f};
    for (int ss = 0; ss < 8; ++ss) {
      s0 += *(const f32x4*)&pan[ss][boff];
      s1 += *(const f32x4*)&pan[ss][boff + 4];
    }
    const int b = b0 + row;
    if constexpr (G1) {
      const float* ca = A.c1Z + (((size_t)k * 64 + p * 2 + ch) * 64 + b) * 8;
      s0 += *(const f32x4*)ca;
      s1 += *(const f32x4*)(ca + 4);
    }
    float v[8];
#pragma unroll
    for (int e = 0; e < 4; ++e) { v[e] = s0[e]; v[4 + e] = s1[e]; }
    if (!fin) {
      u16x8 h8, l8;
#pragma unroll
      for (int e = 0; e < 8; ++e) {
        const u16 hh = bf_rnd(v[e]);
        h8[e] = hh;
        l8[e] = bf_rnd(v[e] - bf_val(hh));
      }
      const size_t zo =
          (((size_t)k * 96 + (G1 ? 32 : 0) + p * 2 + ch) * 64 + b) * 8;
      *(u16x8*)&A.Znh[zo] = h8;
      *(u16x8*)&A.Znl[zo] = l8;
    }
    if constexpr (G1) {
      if (t18) {
#pragma unroll
        for (int e = 0; e < 8; ++e)
          A.out1[((size_t)b * 512 + p * 16 + ch * 8 + e) * 8 + k] = v[e];
      }
    } else {
      if (fin) {
#pragma unroll
        for (int e = 0; e < 8; ++e)
          A.out2[((size_t)b * 256 + p * 16 + ch * 8 + e) * 8 + k] = v[e];
      }
    }
  }
}

__global__ __launch_bounds__(512) void iter_k(IArgs A, int t18, int fin) {
  __shared__ float pan[8][2048];
  if ((int)blockIdx.x < A.n_g1) iter_body<true>(A, t18, fin, pan);
  else iter_body<false>(A, t18, fin, pan);
}

extern "C" void kernel_launch(void* const* d_in, const int* in_sizes, int n_in,
                              void* d_out, int out_size, void* d_ws,
                              size_t ws_size, hipStream_t stream) {
  const float* x = (const float*)d_in[0];
  const float* w1 = (const float*)d_in[1];
  const float* w2 = (const float*)d_in[2];

  float* out0 = (float*)d_out;
  float* out1 = out0 + 131072;
  float* out2 = out1 + 262144;

  char* W = (char*)d_ws;
  const size_t MB = 1ull << 20;
  u16* Vpk1 = (u16*)(W);
  u16* Vpk2 = (u16*)(W + 8 * MB);
  u16* Q1 = (u16*)(W + 14 * MB);
  u16* Q2 = (u16*)(W + 18 * MB);
  u16* Qc1 = (u16*)(W + 22 * MB);
  u16* P1h = (u16*)(W + 26 * MB);
  u16* P1l = (u16*)(W + 28 * MB);
  u16* P2h = (u16*)(W + 30 * MB);
  u16* P2l = (u16*)(W + 32 * MB);
  u16* Axh = (u16*)(W + 34 * MB);
  u16* Axl = (u16*)(W + 34 * MB + 262144);
  float* c1Z = (float*)(W + 35 * MB);
  u16* Z0h = (u16*)(W + 46 * MB);
  u16* Z0l = Z0h + 393216;
  u16* Z1h = Z0h + 786432;
  u16* Z1l = Z0h + 1179648;

  // D1: pack raw inputs
  pack_in<<<2368, 256, 0, stream>>>(x, w1, w2, P1h, P1l, Q1, Qc1, P2h, P2l, Q2,
                                    Axh, Axl, Vpk2, Z0h, Z0l, out0);

  // D2: compose + fused operator pack
  composeK<<<1408, 512, 0, stream>>>(P1h, P1l, Q1, P2h, P2l, Q2, Axh, Axl, Qc1,
                                     Vpk1, Vpk2, Z0h, Z0l, c1Z);

  // D3..D21: 19 stream-ordered pair dispatches {g2_t, g1_{t+1}}
  for (int t = 0; t < 19; ++t) {
    IArgs ia;
    ia.Zch = (t & 1) ? Z1h : Z0h;
    ia.Zcl = (t & 1) ? Z1l : Z0l;
    ia.Znh = (t & 1) ? Z0h : Z1h;
    ia.Znl = (t & 1) ? Z0l : Z1l;
    ia.Vpk1 = Vpk1; ia.Vpk2 = Vpk2; ia.c1Z = c1Z;
    ia.out1 = out1; ia.out2 = nullptr;
    ia.n_g1 = 128;
    iter_k<<<192, 512, 0, stream>>>(ia, t == 18 ? 1 : 0, 0);
  }

  // D22: final g2_19 reads Z1 = [S2_19 | S1_20] -> out2 = S2_20
  {
    IArgs ia;
    ia.Zch = Z1h; ia.Zcl = Z1l;
    ia.Znh = Z0h; ia.Znl = Z0l;  // unused (fin)
    ia.Vpk1 = Vpk1; ia.Vpk2 = Vpk2; ia.c1Z = c1Z;
    ia.out1 = out1; ia.out2 = out2;
    ia.n_g1 = 0;
    iter_k<<<64, 512, 0, stream>>>(ia, 0, 1);
  }
}

// Round 11
// 429.563 us; speedup vs baseline: 1.1079x; 1.1079x over previous
//
#include <hip/hip_runtime.h>

typedef unsigned short u16;
typedef __attribute__((ext_vector_type(4))) float f32x4;
typedef __attribute__((ext_vector_type(8))) __bf16 bf16x8;
typedef __attribute__((ext_vector_type(8))) u16 u16x8;

#define ALPHA_F 0.1f

// Cl(3,0): e_a * e_c = (-1)^p e_{a^c}  [validated R1-R10]
__device__ __host__ constexpr bool SGN(int a, int c) {
  return ((((c & 1) & (((a >> 1) ^ (a >> 2)) & 1)) ^
           (((c >> 1) & 1) & ((a >> 2) & 1))) != 0);
}
__device__ __host__ constexpr float REVF(int c) {
  const int r = (c & 1) + ((c >> 1) & 1) + ((c >> 2) & 1);
  return (r >= 2) ? -1.f : 1.f;
}
__device__ __forceinline__ u16 bf_rnd(float f) {
  unsigned u = __float_as_uint(f);
  return (u16)((u + 0x7FFFu + ((u >> 16) & 1u)) >> 16);
}
__device__ __forceinline__ float bf_val(u16 h) {
  return __uint_as_float(((unsigned)h) << 16);
}
__device__ __forceinline__ f32x4 mf(bf16x8 a, bf16x8 b, f32x4 c) {
  return __builtin_amdgcn_mfma_f32_16x16x32_bf16(a, b, c, 0, 0, 0);
}
__device__ __forceinline__ bf16x8 negf(bf16x8 v) {
  u16x8 u = __builtin_bit_cast(u16x8, v);
  const u16x8 m = {0x8000, 0x8000, 0x8000, 0x8000, 0x8000, 0x8000, 0x8000, 0x8000};
  u = u ^ m;
  return __builtin_bit_cast(bf16x8, u);
}

// ===========================================================================
// D1: pack raw inputs. Q images in V-image layout (validated R8-R10).
// P planes now in CHUNK layout [a][K>>3][row][K&7] so composeK A-loads
// coalesce (16 lanes x 16B contiguous = 256B runs).
// ===========================================================================
__global__ __launch_bounds__(256) void pack_in(
    const float* __restrict__ x, const float* __restrict__ w1,
    const float* __restrict__ w2, u16* P1h, u16* P1l, u16* Q1, u16* Qc1,
    u16* P2h, u16* P2l, u16* Q2, u16* Axh, u16* Axl, u16* Vpk2, u16* Z0h,
    u16* Z0l, float* out0) {
  const int t = blockIdx.x * 256 + threadIdx.x;
  if (t < 131072) {  // Q1 + Qc1 (cc-fast): r = m, cc = n'
    const int r = t >> 9, cc = t & 511;
    const float* s = w1 + ((size_t)r * 512 + cc) * 8;
    float v[8];
#pragma unroll
    for (int c = 0; c < 8; ++c) v[c] = s[c];
    const size_t qo = (size_t)((cc >> 4) * 2 + (r >> 7)) * 32768 +
                      ((r >> 5) & 3) * 512 + ((r >> 3) & 3) * 128 +
                      (cc & 15) * 8 + (r & 7);
#pragma unroll
    for (int c = 0; c < 8; ++c) {
      const float q1 = REVF(c) * v[c];
      u16 h = bf_rnd(q1);
      Q1[qo + c * 4096] = h;
      Q1[qo + c * 4096 + 2048] = bf_rnd(q1 - bf_val(h));
      const float qc = ALPHA_F * q1;
      h = bf_rnd(qc);
      Qc1[qo + c * 4096] = h;
      Qc1[qo + c * 4096 + 2048] = bf_rnd(qc - bf_val(h));
    }
  } else if (t < 262144) {  // Q2 + Wcat-bottom (c2-fast): r = m, c2 = j
    const int u = t - 131072;
    const int r = u >> 8, c2 = u & 255;
    const float* s = w2 + ((size_t)r * 256 + c2) * 8;
    float v[8];
#pragma unroll
    for (int c = 0; c < 8; ++c) v[c] = s[c];
    const size_t tail = ((r >> 5) & 3) * 512 + ((r >> 3) & 3) * 128 +
                        (c2 & 15) * 8 + (r & 7);
    const size_t qo = (size_t)((c2 >> 4) * 4 + (r >> 7)) * 32768 + tail;
    const size_t wo = (size_t)((c2 >> 4) * 6 + 2 + (r >> 7)) * 32768 + tail;
#pragma unroll
    for (int c = 0; c < 8; ++c) {
      const float q2 = REVF(c) * v[c];
      u16 h = bf_rnd(q2);
      Q2[qo + c * 4096] = h;
      Q2[qo + c * 4096 + 2048] = bf_rnd(q2 - bf_val(h));
      const float qw = ALPHA_F * q2;
      h = bf_rnd(qw);
      Vpk2[wo + c * 4096] = h;
      Vpk2[wo + c * 4096 + 2048] = bf_rnd(qw - bf_val(h));
    }
  } else if (t < 393216) {  // P1c chunk planes [a][m>>3][n'][m&7]
    const int u = t - 262144;
    const int r = u & 255, cc = u >> 8;  // r = m, cc = n'
    const float* s = w1 + ((size_t)r * 512 + cc) * 8;
#pragma unroll
    for (int a = 0; a < 8; ++a) {
      const float v = s[a];
      const u16 h = bf_rnd(v);
      const size_t o = ((size_t)(a * 32 + (r >> 3)) * 512 + cc) * 8 + (r & 7);
      P1h[o] = h;
      P1l[o] = bf_rnd(v - bf_val(h));
    }
  } else if (t < 524288) {  // P2c chunk planes [a][m>>3][j][m&7]
    const int u = t - 393216;
    const int r = u & 511, c2 = u >> 9;  // r = m, c2 = j
    const float* s = w2 + ((size_t)r * 256 + c2) * 8;
#pragma unroll
    for (int a = 0; a < 8; ++a) {
      const float v = s[a];
      const u16 h = bf_rnd(v);
      const size_t o = ((size_t)(a * 64 + (r >> 3)) * 256 + c2) * 8 + (r & 7);
      P2h[o] = h;
      P2l[o] = bf_rnd(v - bf_val(h));
    }
  } else if (t < 540672) {  // Axc chunk planes [a][n>>3][b][n&7]
    const int u = t - 524288;
    const int b = u >> 8, n = u & 255;
    const float* s = x + ((size_t)b * 256 + n) * 8;
#pragma unroll
    for (int a = 0; a < 8; ++a) {
      const u16 h = bf_rnd(s[a]);
      const size_t o = ((size_t)(a * 32 + (n >> 3)) * 64 + b) * 8 + (n & 7);
      Axh[o] = h;
      Axl[o] = bf_rnd(s[a] - bf_val(h));
    }
  } else if (t < 573440) {  // out0 = x
    const int u = t - 540672;
    ((float4*)out0)[u] = ((const float4*)x)[u];
  } else if (t < 606208) {  // Z0 S2-region zero
    const int u = t - 573440;
    const int hl = u >> 14, i = u & 16383;
    const int a = i >> 11, j = i & 2047;
    const u16x8 z = {0, 0, 0, 0, 0, 0, 0, 0};
    u16* Z = hl ? Z0l : Z0h;
    *(u16x8*)&Z[(size_t)a * 49152 + (size_t)j * 8] = z;
  }
}

// ===========================================================================
// D2: composeK. R8-R10 core; A-loads now COALESCED via chunk-plane layout;
// pan merge padded (stride 17) to kill 4-way LDS bank conflicts; setprio
// around MFMA clusters. Arithmetic identical.
// ===========================================================================
__global__ __launch_bounds__(512, 2) void composeK(
    const u16* __restrict__ P1h, const u16* __restrict__ P1l,
    const u16* __restrict__ Q1, const u16* __restrict__ P2h,
    const u16* __restrict__ P2l, const u16* __restrict__ Q2,
    const u16* __restrict__ Axh, const u16* __restrict__ Axl,
    const u16* __restrict__ Qc1, u16* Vpk1, u16* Vpk2, u16* Z0h, u16* Z0l,
    float* c1Z) {
  __shared__ float pan[8][2176];  // [wave][(k*16+row)*17 + col]

  const int bid = blockIdx.x, tid = threadIdx.x;
  const int w = tid >> 6, l = tid & 63;
  const int lg = l >> 4, lm = l & 15;

  int seg, rb, p;
  if (bid < 256) { seg = 1; rb = bid >> 4; p = bid & 15; }
  else if (bid < 1280) { seg = 0; rb = (bid - 256) >> 5; p = (bid - 256) & 31; }
  else { seg = 2; rb = (bid - 1280) >> 5; p = (bid - 1280) & 31; }

  const u16* Ah_ = seg == 0 ? P1h : (seg == 1 ? P2h : Axh);
  const u16* Al_ = seg == 0 ? P1l : (seg == 1 ? P2l : Axl);
  const u16* Vb = seg == 0 ? Q1 : (seg == 1 ? Q2 : Qc1);
  const int NROW = seg == 0 ? 512 : (seg == 1 ? 256 : 64);
  const int KC = seg == 1 ? 64 : 32;  // K chunks (K/8)
  const int NW = seg == 1 ? 2 : 1;
  const int slmul = seg == 1 ? 4 : 2;
  const int row = rb * 16 + lm;

  f32x4 acc[8];
#pragma unroll
  for (int k = 0; k < 8; ++k) acc[k] = f32x4{0.f, 0.f, 0.f, 0.f};

  for (int wi = 0; wi < NW; ++wi) {
    const int n0 = w * (NW * 32) + wi * 32;
    const int sl = n0 >> 7, hst = (n0 >> 5) & 3;
    const u16* Vimg =
        Vb + ((size_t)(p * slmul + sl) << 15) + hst * 512 + lg * 128 + lm * 8;
    const int kc = (n0 >> 3) + lg;
    bf16x8 ah[8], al[8];
#pragma unroll
    for (int a = 0; a < 8; ++a) {
      const size_t o = ((size_t)(a * KC + kc) * NROW + row) * 8;
      ah[a] = *(const bf16x8*)(Ah_ + o);
      al[a] = *(const bf16x8*)(Al_ + o);
    }
    __builtin_amdgcn_s_setprio(1);
#pragma unroll
    for (int c = 0; c < 8; ++c) {
      const bf16x8 vhp = *(const bf16x8*)(Vimg + (size_t)c * 4096);
      const bf16x8 vlp = *(const bf16x8*)(Vimg + (size_t)c * 4096 + 2048);
      const bf16x8 vhn = negf(vhp), vln = negf(vlp);
#pragma unroll
      for (int a = 0; a < 8; ++a) {
        const int k = a ^ c;
        const bf16x8 vh = SGN(a, c) ? vhn : vhp;
        const bf16x8 vl = SGN(a, c) ? vln : vlp;
        acc[k] = mf(ah[a], vh, acc[k]);
        acc[k] = mf(al[a], vh, acc[k]);
        acc[k] = mf(ah[a], vl, acc[k]);
      }
    }
    __builtin_amdgcn_s_setprio(0);
  }

#pragma unroll
  for (int k = 0; k < 8; ++k)
#pragma unroll
    for (int q = 0; q < 4; ++q)
      pan[w][(k * 16 + lg * 4 + q) * 17 + lm] = acc[k][q];
  __syncthreads();

  if (tid < 256) {
    const int k = tid >> 5, rw = (tid >> 1) & 15, ch = tid & 1;
    const int boff = (k * 16 + rw) * 17 + ch * 8;
    f32x4 s0 = {0.f, 0.f, 0.f, 0.f}, s1 = {0.f, 0.f, 0.f, 0.f};
    for (int ss = 0; ss < 8; ++ss) {
      s0 += *(const f32x4*)&pan[ss][boff];
      s1 += *(const f32x4*)&pan[ss][boff + 4];
    }
    float v[8];
#pragma unroll
    for (int e = 0; e < 4; ++e) { v[e] = s0[e]; v[4 + e] = s1[e]; }
    const int n = rb * 16 + rw;

    if (seg <= 1) {
      u16* base = seg == 0 ? Vpk1 : Vpk2;
      const int blk = (seg == 0 ? p * 4 : p * 6) + (n >> 7);
      u16* d = base + ((size_t)blk << 15) + (size_t)k * 4096 +
               ((n >> 5) & 3) * 512 + ((n >> 3) & 3) * 128 + (n & 7);
#pragma unroll
      for (int e = 0; e < 8; ++e) {
        const int m = p * 16 + ch * 8 + e;
        const float val = ((k == 0) && (n == m) ? 1.0f : 0.0f) - ALPHA_F * v[e];
        const u16 hh = bf_rnd(val);
        d[(size_t)(ch * 8 + e) * 8] = hh;
        d[2048 + (size_t)(ch * 8 + e) * 8] = bf_rnd(val - bf_val(hh));
      }
    } else {
      const int b = n;
      float* cp_ = c1Z + (((size_t)k * 64 + p * 2 + ch) * 64 + b) * 8;
      u16x8 h8, l8;
#pragma unroll
      for (int e = 0; e < 8; ++e) {
        cp_[e] = v[e];
        const u16 hh = bf_rnd(v[e]);
        h8[e] = hh;
        l8[e] = bf_rnd(v[e] - bf_val(hh));
      }
      const size_t zo = (((size_t)k * 96 + 32 + p * 2 + ch) * 64 + b) * 8;
      *(u16x8*)&Z0h[zo] = h8;
      *(u16x8*)&Z0l[zo] = l8;
    }
  }
}

// ===========================================================================
// Main-loop pair kernel. R10 structure + __launch_bounds__(512,2) (VGPR cap
// 256 -> compiler hoists next-window loads), setprio around MFMA, padded pan.
// Arithmetic order IDENTICAL to R7-R10.
// ===========================================================================
struct IArgs {
  const u16 *Zch, *Zcl;
  u16 *Znh, *Znl;
  const u16 *Vpk1, *Vpk2;
  const float* c1Z;
  float *out1, *out2;
  int n_g1;
};

template <bool G1>
__device__ __forceinline__ void iter_body(const IArgs& A, int t18, int fin,
                                          float (*pan)[2176]) {
  const int bid = blockIdx.x, tid = threadIdx.x;
  const int w = tid >> 6, l = tid & 63;
  const int lg = l >> 4, lm = l & 15;
  const int rb = G1 ? bid : bid - A.n_g1;
  constexpr int NPAN = G1 ? 32 : 16;
  const int p = rb & (NPAN - 1);  // XCD-affine (R10)
  const int bh = rb / NPAN;
  const int b0 = bh * 16;
  constexpr int KW = G1 ? 64 : 96;
  constexpr int NW = G1 ? 2 : 3;
  constexpr int acb0 = G1 ? 32 : 0;
  constexpr int slmul = G1 ? 4 : 6;
  const u16* Vb = G1 ? A.Vpk1 : A.Vpk2;

  f32x4 acc[8];
#pragma unroll
  for (int k = 0; k < 8; ++k) acc[k] = f32x4{0.f, 0.f, 0.f, 0.f};

#pragma unroll
  for (int wi = 0; wi < NW; ++wi) {
    const int n0 = w * KW + wi * 32;
    const int sl = n0 >> 7, hst = (n0 >> 5) & 3;
    const u16* Vimg = Vb + ((size_t)(p * slmul + sl) << 15) + hst * 512 +
                      lg * 128 + lm * 8;
    const size_t ao = ((size_t)(acb0 + (n0 >> 3) + lg) * 64 + b0 + lm) * 8;
    bf16x8 ah[8], al[8];
#pragma unroll
    for (int a = 0; a < 8; ++a) {
      ah[a] = *(const bf16x8*)(A.Zch + (size_t)a * 49152 + ao);
      al[a] = *(const bf16x8*)(A.Zcl + (size_t)a * 49152 + ao);
    }
    __builtin_amdgcn_s_setprio(1);
#pragma unroll
    for (int c = 0; c < 8; ++c) {
      const bf16x8 vhp = *(const bf16x8*)(Vimg + (size_t)c * 4096);
      const bf16x8 vlp = *(const bf16x8*)(Vimg + (size_t)c * 4096 + 2048);
      const bf16x8 vhn = negf(vhp), vln = negf(vlp);
#pragma unroll
      for (int a = 0; a < 8; ++a) {
        const int k = a ^ c;
        const bf16x8 vh = SGN(a, c) ? vhn : vhp;
        const bf16x8 vl = SGN(a, c) ? vln : vlp;
        acc[k] = mf(ah[a], vh, acc[k]);
        acc[k] = mf(al[a], vh, acc[k]);
        acc[k] = mf(ah[a], vl, acc[k]);
      }
    }
    __builtin_amdgcn_s_setprio(0);
  }

#pragma unroll
  for (int k = 0; k < 8; ++k)
#pragma unroll
    for (int q = 0; q < 4; ++q)
      pan[w][(k * 16 + lg * 4 + q) * 17 + lm] = acc[k][q];
  __syncthreads();

  if (tid < 256) {
    const int k = tid >> 5, row = (tid >> 1) & 15, ch = tid & 1;
    const int boff = (k * 16 + row) * 17 + ch * 8;
    f32x4 s0 = {0.f, 0.f, 0.f, 0.f}, s1 = {0.f, 0.f, 0.f, 0.f};
    for (int ss = 0; ss < 8; ++ss) {
      s0 += *(const f32x4*)&pan[ss][boff];
      s1 += *(const f32x4*)&pan[ss][boff + 4];
    }
    const int b = b0 + row;
    if constexpr (G1) {
      const float* ca = A.c1Z + (((size_t)k * 64 + p * 2 + ch) * 64 + b) * 8;
      s0 += *(const f32x4*)ca;
      s1 += *(const f32x4*)(ca + 4);
    }
    float v[8];
#pragma unroll
    for (int e = 0; e < 4; ++e) { v[e] = s0[e]; v[4 + e] = s1[e]; }
    if (!fin) {
      u16x8 h8, l8;
#pragma unroll
      for (int e = 0; e < 8; ++e) {
        const u16 hh = bf_rnd(v[e]);
        h8[e] = hh;
        l8[e] = bf_rnd(v[e] - bf_val(hh));
      }
      const size_t zo =
          (((size_t)k * 96 + (G1 ? 32 : 0) + p * 2 + ch) * 64 + b) * 8;
      *(u16x8*)&A.Znh[zo] = h8;
      *(u16x8*)&A.Znl[zo] = l8;
    }
    if constexpr (G1) {
      if (t18) {
#pragma unroll
        for (int e = 0; e < 8; ++e)
          A.out1[((size_t)b * 512 + p * 16 + ch * 8 + e) * 8 + k] = v[e];
      }
    } else {
      if (fin) {
#pragma unroll
        for (int e = 0; e < 8; ++e)
          A.out2[((size_t)b * 256 + p * 16 + ch * 8 + e) * 8 + k] = v[e];
      }
    }
  }
}

__global__ __launch_bounds__(512, 2) void iter_k(IArgs A, int t18, int fin) {
  __shared__ float pan[8][2176];
  if ((int)blockIdx.x < A.n_g1) iter_body<true>(A, t18, fin, pan);
  else iter_body<false>(A, t18, fin, pan);
}

extern "C" void kernel_launch(void* const* d_in, const int* in_sizes, int n_in,
                              void* d_out, int out_size, void* d_ws,
                              size_t ws_size, hipStream_t stream) {
  const float* x = (const float*)d_in[0];
  const float* w1 = (const float*)d_in[1];
  const float* w2 = (const float*)d_in[2];

  float* out0 = (float*)d_out;
  float* out1 = out0 + 131072;
  float* out2 = out1 + 262144;

  char* W = (char*)d_ws;
  const size_t MB = 1ull << 20;
  u16* Vpk1 = (u16*)(W);
  u16* Vpk2 = (u16*)(W + 8 * MB);
  u16* Q1 = (u16*)(W + 14 * MB);
  u16* Q2 = (u16*)(W + 18 * MB);
  u16* Qc1 = (u16*)(W + 22 * MB);
  u16* P1h = (u16*)(W + 26 * MB);
  u16* P1l = (u16*)(W + 28 * MB);
  u16* P2h = (u16*)(W + 30 * MB);
  u16* P2l = (u16*)(W + 32 * MB);
  u16* Axh = (u16*)(W + 34 * MB);
  u16* Axl = (u16*)(W + 34 * MB + 262144);
  float* c1Z = (float*)(W + 35 * MB);
  u16* Z0h = (u16*)(W + 46 * MB);
  u16* Z0l = Z0h + 393216;
  u16* Z1h = Z0h + 786432;
  u16* Z1l = Z0h + 1179648;

  // D1: pack raw inputs
  pack_in<<<2368, 256, 0, stream>>>(x, w1, w2, P1h, P1l, Q1, Qc1, P2h, P2l, Q2,
                                    Axh, Axl, Vpk2, Z0h, Z0l, out0);

  // D2: compose + fused operator pack
  composeK<<<1408, 512, 0, stream>>>(P1h, P1l, Q1, P2h, P2l, Q2, Axh, Axl, Qc1,
                                     Vpk1, Vpk2, Z0h, Z0l, c1Z);

  // D3..D21: 19 stream-ordered pair dispatches {g2_t, g1_{t+1}}
  for (int t = 0; t < 19; ++t) {
    IArgs ia;
    ia.Zch = (t & 1) ? Z1h : Z0h;
    ia.Zcl = (t & 1) ? Z1l : Z0l;
    ia.Znh = (t & 1) ? Z0h : Z1h;
    ia.Znl = (t & 1) ? Z0l : Z1l;
    ia.Vpk1 = Vpk1; ia.Vpk2 = Vpk2; ia.c1Z = c1Z;
    ia.out1 = out1; ia.out2 = nullptr;
    ia.n_g1 = 128;
    iter_k<<<192, 512, 0, stream>>>(ia, t == 18 ? 1 : 0, 0);
  }

  // D22: final g2_19 reads Z1 = [S2_19 | S1_20] -> out2 = S2_20
  {
    IArgs ia;
    ia.Zch = Z1h; ia.Zcl = Z1l;
    ia.Znh = Z0h; ia.Znl = Z0l;  // unused (fin)
    ia.Vpk1 = Vpk1; ia.Vpk2 = Vpk2; ia.c1Z = c1Z;
    ia.out1 = out1; ia.out2 = out2;
    ia.n_g1 = 0;
    iter_k<<<64, 512, 0, stream>>>(ia, 0, 1);
  }
}